// Round 7
// baseline (107.012 us; speedup 1.0000x reference)
//
#include <hip/hip_runtime.h>

#define KCODES 512
#define DDIM   64
#define NROWS  131072

typedef short bf16x8 __attribute__((ext_vector_type(8)));
typedef float f32x4  __attribute__((ext_vector_type(4)));
typedef int   i32x4  __attribute__((ext_vector_type(4)));

union frag_cast { i32x4 i; bf16x8 h; };

__device__ __forceinline__ unsigned f32_to_bf16_rne(float x) {
    unsigned u = __float_as_uint(x);
    return (u + 0x7fffu + ((u >> 16) & 1u)) >> 16;   // RNE (finite/normal data)
}

// ---------------- K1a: e_norm[k] + emax ----------------
__global__ __launch_bounds__(512) void k1_enorm(const float* __restrict__ emb,
                                                float* __restrict__ en, float* __restrict__ emaxp) {
    __shared__ float red[512];
    int k = threadIdx.x;
    float s = 0.f;
#pragma unroll
    for (int d = 0; d < DDIM; ++d) { float e = emb[k * DDIM + d]; s = fmaf(e, e, s); }
    en[k] = s;
    red[k] = s;
    __syncthreads();
    for (int st = 256; st > 0; st >>= 1) {
        if (k < st) red[k] = fmaxf(red[k], red[k + st]);
        __syncthreads();
    }
    if (k == 0) emaxp[0] = sqrtf(red[0]) * 1.0001f;
}

// ---------------- K1b: codebook -> split-bf16 B-fragments (hi, lo) ----------------
// chunk (kt,c,lane): lane holds e[kt*16+(lane&15)][c*32+(lane>>4)*8 + j], j=0..7
__global__ __launch_bounds__(128) void k1_efrag(const float* __restrict__ emb,
                                                i32x4* __restrict__ efA, i32x4* __restrict__ efB) {
    int kt = blockIdx.x, t = threadIdx.x;
    int c = t >> 6, lane = t & 63;
    int krow = kt * 16 + (lane & 15);
    int d0 = c * 32 + ((lane >> 4) * 8);
    const float* src = emb + krow * DDIM + d0;
    unsigned hh[8], hl[8];
#pragma unroll
    for (int j = 0; j < 8; ++j) {
        float x = src[j];
        unsigned h = f32_to_bf16_rne(x);
        float hf = __uint_as_float(h << 16);
        hh[j] = h;
        hl[j] = f32_to_bf16_rne(x - hf);
    }
    i32x4 wh, wl;
#pragma unroll
    for (int i = 0; i < 4; ++i) {
        wh[i] = (int)(hh[2 * i] | (hh[2 * i + 1] << 16));
        wl[i] = (int)(hl[2 * i] | (hl[2 * i + 1] << 16));
    }
    efA[(kt * 2 + c) * 64 + lane] = wh;
    efB[(kt * 2 + c) * 64 + lane] = wl;
}

// ---------------- K3: fused, LDS-dbuf e-frags, 4 waves x 2 tiles = 128 rows ----------
// grid = 1024 blocks; ~36.6 KB LDS -> 4 blocks/CU, 16 waves/CU
__global__ __launch_bounds__(256, 4) void k3_fused(
    const float* __restrict__ z,
    const i32x4* __restrict__ efA_, const i32x4* __restrict__ efB_,
    const float* __restrict__ en_g, float* __restrict__ zn_g,
    const float* __restrict__ emaxp, int* __restrict__ out,
    int* __restrict__ list, int* __restrict__ cnt) {

    // region: prologue z-transpose [64][133] f32; main loop: frag dbuf
    // frag layout (i32x4 units): [buf]{0,1}*1024 + [hi=0|lo=512] + q(0..511),
    // q = (ktl*2+c)*64 + lane
    __shared__ float region[DDIM * 133];   // 34048 B >= 32768 B frag dbuf
    __shared__ float en_l[KCODES];
    __shared__ float zn_l[128];

    const int t = threadIdx.x, blk = blockIdx.x;
    const int n0 = blk * 128;
    const int b = n0 >> 12, hw0 = n0 & 4095;   // 32 blocks per b -> b uniform

    i32x4* frag = (i32x4*)region;

    // ---- P1: waves 0,1 load z columns + zn (sequential-d chain, k4 semantics);
    //          waves 2,3 load en + chunk0 frags into regs
    i32x4 s0h, s1h, s2h, s3h, s0l, s1l, s2l, s3l;
    if (t < 128) {
        const float* zb = z + (size_t)b * (DDIM * 4096) + hw0 + t;
        float s = 0.f;
#pragma unroll
        for (int d = 0; d < DDIM; ++d) {
            float v = zb[(size_t)d * 4096];
            region[d * 133 + t] = v;
            s = fmaf(v, v, s);
        }
        zn_l[t] = s;
        zn_g[n0 + t] = s;
    } else {
        int t2 = t - 128;
        en_l[t2]       = en_g[t2];
        en_l[t2 + 128] = en_g[t2 + 128];
        en_l[t2 + 256] = en_g[t2 + 256];
        en_l[t2 + 384] = en_g[t2 + 384];
        s0h = efA_[t2]; s1h = efA_[t2 + 128]; s2h = efA_[t2 + 256]; s3h = efA_[t2 + 384];
        s0l = efB_[t2]; s1l = efB_[t2 + 128]; s2l = efB_[t2 + 256]; s3l = efB_[t2 + 384];
    }
    __syncthreads();

    // ---- P2: every wave extracts split-bf16 A-frags for its 2 row-tiles
    const int w = t >> 6, lane = t & 63;
    const int klane = lane & 15, g = lane >> 4;
    const float emax = emaxp[0];

    bf16x8 zh[2][2], zl[2][2];
#pragma unroll
    for (int tl = 0; tl < 2; ++tl) {
        int rowl = w * 32 + tl * 16 + klane;
#pragma unroll
        for (int c = 0; c < 2; ++c) {
            int d0 = c * 32 + g * 8;
            unsigned hh[8], hl[8];
#pragma unroll
            for (int j = 0; j < 8; ++j) {
                float x = region[(d0 + j) * 133 + rowl];
                unsigned h = f32_to_bf16_rne(x);
                float hf = __uint_as_float(h << 16);
                hh[j] = h;
                hl[j] = f32_to_bf16_rne(x - hf);
            }
            frag_cast uh, ul;
#pragma unroll
            for (int i = 0; i < 4; ++i) {
                uh.i[i] = (int)(hh[2 * i] | (hh[2 * i + 1] << 16));
                ul.i[i] = (int)(hl[2 * i] | (hl[2 * i + 1] << 16));
            }
            zh[tl][c] = uh.h;
            zl[tl][c] = ul.h;
        }
    }
    f32x4 zn4[2];
    zn4[0] = *(const f32x4*)&zn_l[w * 32 + g * 4];
    zn4[1] = *(const f32x4*)&zn_l[w * 32 + 16 + g * 4];
    __syncthreads();   // all reads of region done

    // ---- P3: waves 2,3 write chunk0 into buf0
    if (t >= 128) {
        int t2 = t - 128;
        frag[t2]             = s0h; frag[t2 + 128]       = s1h;
        frag[t2 + 256]       = s2h; frag[t2 + 384]       = s3h;
        frag[512 + t2]       = s0l; frag[512 + t2 + 128] = s1l;
        frag[512 + t2 + 256] = s2l; frag[512 + t2 + 384] = s3l;
    }

    float m1[2][4], m2[2][4];
    int i1[2][4];
#pragma unroll
    for (int tl = 0; tl < 2; ++tl)
#pragma unroll
        for (int r = 0; r < 4; ++r) { m1[tl][r] = 3.4e38f; m2[tl][r] = 3.4e38f; i1[tl][r] = 0; }

    f32x4 zero = {0.f, 0.f, 0.f, 0.f};
    i32x4 lA0, lA1, lB0, lB1;

    // ---- main: 8 chunks x 4 kt; dbuf pipeline, 1 barrier/chunk
    for (int c0 = 0; c0 < 8; ++c0) {
        const int buf = c0 & 1;
        if (c0 < 7) {   // issue next chunk's global loads early (latency hides under compute)
            int base = (c0 + 1) * 512;
            lA0 = efA_[base + t];       lA1 = efA_[base + 256 + t];
            lB0 = efB_[base + t];       lB1 = efB_[base + 256 + t];
        }
        __syncthreads();   // buf[c0&1] writes (P3 / prev iter) visible

        const bf16x8* fh = (const bf16x8*)&frag[buf * 1024];
        const bf16x8* fl = (const bf16x8*)&frag[buf * 1024 + 512];
#pragma unroll
        for (int ktl = 0; ktl < 4; ++ktl) {
            bf16x8 e0h = fh[(ktl * 2 + 0) * 64 + lane];
            bf16x8 e1h = fh[(ktl * 2 + 1) * 64 + lane];
            bf16x8 e0l = fl[(ktl * 2 + 0) * 64 + lane];
            bf16x8 e1l = fl[(ktl * 2 + 1) * 64 + lane];
            int k = (c0 * 4 + ktl) * 16 + klane;
            float enk = en_l[k];
#pragma unroll
            for (int tl = 0; tl < 2; ++tl) {
                f32x4 acc = __builtin_amdgcn_mfma_f32_16x16x32_bf16(zh[tl][0], e0h, zero, 0, 0, 0);
                acc = __builtin_amdgcn_mfma_f32_16x16x32_bf16(zh[tl][1], e1h, acc, 0, 0, 0);
                acc = __builtin_amdgcn_mfma_f32_16x16x32_bf16(zh[tl][0], e0l, acc, 0, 0, 0);
                acc = __builtin_amdgcn_mfma_f32_16x16x32_bf16(zh[tl][1], e1l, acc, 0, 0, 0);
                acc = __builtin_amdgcn_mfma_f32_16x16x32_bf16(zl[tl][0], e0h, acc, 0, 0, 0);
                acc = __builtin_amdgcn_mfma_f32_16x16x32_bf16(zl[tl][1], e1h, acc, 0, 0, 0);
#pragma unroll
                for (int r = 0; r < 4; ++r) {
                    float d = fmaf(-2.f, acc[r], zn4[tl][r] + enk);  // refine-path rounding
                    float o1 = m1[tl][r];
                    i1[tl][r] = (d < o1) ? k : i1[tl][r];
                    m2[tl][r] = fminf(m2[tl][r], fmaxf(o1, d));
                    m1[tl][r] = fminf(o1, d);
                }
            }
        }
        if (c0 < 7) {   // write next chunk (other buffer; readers of it are barrier-separated)
            int base2 = ((c0 + 1) & 1) * 1024;
            frag[base2 + t]             = lA0;
            frag[base2 + 256 + t]       = lA1;
            frag[base2 + 512 + t]       = lB0;
            frag[base2 + 512 + 256 + t] = lB1;
        }
    }

    // reduce across the 16 code-lanes: xor 1,2,4,8
#pragma unroll
    for (int sh = 1; sh <= 8; sh <<= 1) {
#pragma unroll
        for (int tl = 0; tl < 2; ++tl)
#pragma unroll
            for (int r = 0; r < 4; ++r) {
                float om1 = __shfl_xor(m1[tl][r], sh);
                int oi1 = __shfl_xor(i1[tl][r], sh);
                float om2 = __shfl_xor(m2[tl][r], sh);
                float hi = fmaxf(m1[tl][r], om1);
                m2[tl][r] = fminf(fminf(m2[tl][r], om2), hi);
                i1[tl][r] = (om1 < m1[tl][r]) ? oi1 : i1[tl][r];
                m1[tl][r] = fminf(m1[tl][r], om1);
            }
    }

    if (klane == 0) {
#pragma unroll
        for (int tl = 0; tl < 2; ++tl) {
            int rowbase = n0 + w * 32 + tl * 16 + g * 4;
            i32x4 idx4;
#pragma unroll
            for (int r = 0; r < 4; ++r) idx4[r] = i1[tl][r];
            *(i32x4*)(out + rowbase) = idx4;
#pragma unroll
            for (int r = 0; r < 4; ++r) {
                float zz = zn4[tl][r];
                // |split-mfma dist - seq-fp32 dist| bound (~3x margin), validated r5/r6
                float W = fmaf(sqrtf(zz) * emax, 1.0e-4f, zz * 1.0e-6f);
                if (m2[tl][r] - m1[tl][r] <= W) {
                    int pos = atomicAdd(cnt, 1);
                    list[pos] = rowbase + r;
                }
            }
        }
    }
}

// ---------------- K4: exact fp32 refine, one wave per listed row ----------------
__global__ __launch_bounds__(256) void k4_refine(
    const float* __restrict__ z, const float* __restrict__ emb,
    const float* __restrict__ en, const float* __restrict__ zn_g,
    const int* __restrict__ list, const int* __restrict__ cnt,
    int* __restrict__ out) {
    __shared__ float zrow[4][64];
    int t = threadIdx.x;
    int w = t >> 6, lane = t & 63;
    int nlist = cnt[0];
    for (int li = blockIdx.x * 4 + w; li < nlist; li += gridDim.x * 4) {
        int row = list[li];
        int b = row >> 12, hw = row & 4095;
        const float* zp = z + (size_t)b * (DDIM * 4096) + hw;
        zrow[w][lane] = zp[(size_t)lane * 4096];
        float zn = zn_g[row];
        float best = 3.4e38f;
        int bi = 0;
#pragma unroll 1
        for (int kk = 0; kk < 8; ++kk) {
            int k = lane * 8 + kk;
            const float* e0 = emb + k * DDIM;
            float acc = 0.f;
#pragma unroll
            for (int d = 0; d < DDIM; ++d) acc = fmaf(e0[d], zrow[w][d], acc);
            float dist = fmaf(-2.f, acc, zn + en[k]);
            if (dist < best) { best = dist; bi = k; }   // ascending k: first-occurrence
        }
        unsigned long long key =
            ((unsigned long long)__float_as_uint(best) << 32) | (unsigned)bi;
#pragma unroll
        for (int sh = 32; sh; sh >>= 1) {
            unsigned long long o = __shfl_xor(key, sh);
            key = (o < key) ? o : key;
        }
        if (lane == 0) out[row] = (int)(key & 0xFFFFFFFFull);
    }
}

// ---------------- fallback (round-1, known-good) ----------------
__global__ void fb_enorm(const float* __restrict__ emb, float* __restrict__ en) {
    int k = blockIdx.x * blockDim.x + threadIdx.x;
    if (k < KCODES) {
        float s = 0.f;
#pragma unroll
        for (int d = 0; d < DDIM; ++d) { float e = emb[k * DDIM + d]; s = fmaf(e, e, s); }
        en[k] = s;
    }
}
__global__ __launch_bounds__(256) void fb_argmin(const float* __restrict__ z,
                                                 const float* __restrict__ emb,
                                                 const float* __restrict__ en,
                                                 int* __restrict__ out, int nrows) {
    int n = blockIdx.x * blockDim.x + threadIdx.x;
    if (n >= nrows) return;
    int b = n >> 12, hw = n & 4095;
    const float* zp = z + (size_t)b * (DDIM * 4096) + hw;
    float zr[DDIM];
#pragma unroll
    for (int d = 0; d < DDIM; ++d) zr[d] = zp[(size_t)d * 4096];
    float zn = 0.f;
#pragma unroll
    for (int d = 0; d < DDIM; ++d) zn = fmaf(zr[d], zr[d], zn);
    float best = 3.4e38f; int bi = 0;
    for (int k0 = 0; k0 < KCODES; k0 += 8) {
        float acc[8];
#pragma unroll
        for (int kk = 0; kk < 8; ++kk) acc[kk] = 0.f;
        const float* e0 = emb + k0 * DDIM;
#pragma unroll
        for (int d = 0; d < DDIM; ++d) {
            float zd = zr[d];
#pragma unroll
            for (int kk = 0; kk < 8; ++kk) acc[kk] = fmaf(e0[kk * DDIM + d], zd, acc[kk]);
        }
#pragma unroll
        for (int kk = 0; kk < 8; ++kk) {
            float dist = fmaf(-2.f, acc[kk], zn + en[k0 + kk]);
            if (dist < best) { best = dist; bi = k0 + kk; }
        }
    }
    out[n] = bi;
}

extern "C" void kernel_launch(void* const* d_in, const int* in_sizes, int n_in,
                              void* d_out, int out_size, void* d_ws, size_t ws_size,
                              hipStream_t stream) {
    const float* z   = (const float*)d_in[0];   // [32,64,64,64] fp32
    const float* emb = (const float*)d_in[1];   // [512,64] fp32
    int* out = (int*)d_out;                     // 131072 int32

    const size_t SZ_EF   = 32 * 2 * 64 * 16;    // 64 KB each
    const size_t SZ_EN   = KCODES * 4;
    const size_t SZ_ZN   = (size_t)NROWS * 4;
    const size_t SZ_EMAX = 64;
    const size_t SZ_LIST = (size_t)NROWS * 4;
    const size_t SZ_CNT  = 64;
    const size_t NEED = 2 * SZ_EF + SZ_EN + SZ_ZN + SZ_EMAX + SZ_LIST + SZ_CNT;  // ~1.2 MB

    if (ws_size < NEED) {   // safety net: round-1 path
        float* en = (float*)d_ws;
        fb_enorm<<<2, 256, 0, stream>>>(emb, en);
        fb_argmin<<<NROWS / 256, 256, 0, stream>>>(z, emb, en, out, NROWS);
        return;
    }

    char* p = (char*)d_ws;
    i32x4* efA = (i32x4*)p;   p += SZ_EF;
    i32x4* efB = (i32x4*)p;   p += SZ_EF;
    float* en  = (float*)p;   p += SZ_EN;
    float* zn  = (float*)p;   p += SZ_ZN;
    float* emaxp = (float*)p; p += SZ_EMAX;
    int* list = (int*)p;      p += SZ_LIST;
    int* cnt  = (int*)p;

    k1_enorm<<<1, 512, 0, stream>>>(emb, en, emaxp);
    k1_efrag<<<32, 128, 0, stream>>>(emb, efA, efB);
    hipMemsetAsync(cnt, 0, 4, stream);

    k3_fused<<<NROWS / 128, 256, 0, stream>>>(z, efA, efB, en, zn, emaxp, out, list, cnt);
    k4_refine<<<512, 256, 0, stream>>>(z, emb, en, zn, list, cnt, out);
}

// Round 8
// 84.132 us; speedup vs baseline: 1.2720x; 1.2720x over previous
//
#include <hip/hip_runtime.h>

#define KCODES 512
#define DDIM   64
#define NROWS  131072

typedef short bf16x8 __attribute__((ext_vector_type(8)));
typedef float f32x4  __attribute__((ext_vector_type(4)));
typedef int   i32x4  __attribute__((ext_vector_type(4)));

union frag_cast { i32x4 i; bf16x8 h; };

__device__ __forceinline__ unsigned f32_to_bf16_rne(float x) {
    unsigned u = __float_as_uint(x);
    return (u + 0x7fffu + ((u >> 16) & 1u)) >> 16;   // RNE (finite/normal data)
}

// ---------------- K1a: e_norm[k] + emax ----------------
__global__ __launch_bounds__(512) void k1_enorm(const float* __restrict__ emb,
                                                float* __restrict__ en, float* __restrict__ emaxp) {
    __shared__ float red[512];
    int k = threadIdx.x;
    float s = 0.f;
#pragma unroll
    for (int d = 0; d < DDIM; ++d) { float e = emb[k * DDIM + d]; s = fmaf(e, e, s); }
    en[k] = s;
    red[k] = s;
    __syncthreads();
    for (int st = 256; st > 0; st >>= 1) {
        if (k < st) red[k] = fmaxf(red[k], red[k + st]);
        __syncthreads();
    }
    if (k == 0) emaxp[0] = sqrtf(red[0]) * 1.0001f;
}

// ---------------- K1b: codebook -> split-bf16 B-fragments (hi, lo) ----------------
// chunk (kt,c,lane): lane holds e[kt*16+(lane&15)][c*32+(lane>>4)*8 + j], j=0..7
__global__ __launch_bounds__(128) void k1_efrag(const float* __restrict__ emb,
                                                i32x4* __restrict__ efA, i32x4* __restrict__ efB) {
    int kt = blockIdx.x, t = threadIdx.x;
    int c = t >> 6, lane = t & 63;
    int krow = kt * 16 + (lane & 15);
    int d0 = c * 32 + ((lane >> 4) * 8);
    const float* src = emb + krow * DDIM + d0;
    unsigned hh[8], hl[8];
#pragma unroll
    for (int j = 0; j < 8; ++j) {
        float x = src[j];
        unsigned h = f32_to_bf16_rne(x);
        float hf = __uint_as_float(h << 16);
        hh[j] = h;
        hl[j] = f32_to_bf16_rne(x - hf);
    }
    i32x4 wh, wl;
#pragma unroll
    for (int i = 0; i < 4; ++i) {
        wh[i] = (int)(hh[2 * i] | (hh[2 * i + 1] << 16));
        wl[i] = (int)(hl[2 * i] | (hl[2 * i + 1] << 16));
    }
    efA[(kt * 2 + c) * 64 + lane] = wh;
    efB[(kt * 2 + c) * 64 + lane] = wl;
}

// ---------------- K3: fused, direct z-gather, LDS-dbuf e-frags ----------------
// block = 4 waves x 2 tiles = 128 rows; LDS 34.8 KB -> 3-4 blocks/CU, 12 waves/CU
__global__ __launch_bounds__(256, 3) void k3_fused(
    const float* __restrict__ z,
    const i32x4* __restrict__ efA_, const i32x4* __restrict__ efB_,
    const float* __restrict__ en_g, float* __restrict__ zn_g,
    const float* __restrict__ emaxp, int* __restrict__ out,
    int* __restrict__ list, int* __restrict__ cnt) {

    __shared__ i32x4 frag[2048];     // 32 KB dbuf: buf*1024 + (hi:0|lo:512) + (ktl*2+c)*64+lane
    __shared__ float en_l[KCODES];   // 2 KB
    __shared__ float zn_l[128];

    const int t = threadIdx.x, blk = blockIdx.x;
    const int n0 = blk * 128;
    const int b = n0 >> 12, hw0 = n0 & 4095;   // 32 blocks per b -> b uniform
    const int w = t >> 6, lane = t & 63;
    const int klane = lane & 15, g = lane >> 4;

    // ---- prologue: chunk0 frags + en -> LDS; z gathered straight to regs
    i32x4 c0a = efA_[t], c0b = efA_[256 + t];
    i32x4 c0c = efB_[t], c0d = efB_[256 + t];
    float ena = en_g[t], enb = en_g[t + 256];

    const float* zbase = z + (size_t)b * (DDIM * 4096) + hw0;
    float zv[2][16];   // per thread: rows w*32+tl*16+klane, d = c*32+g*8+j
#pragma unroll
    for (int tl = 0; tl < 2; ++tl) {
        int row = w * 32 + tl * 16 + klane;
#pragma unroll
        for (int c = 0; c < 2; ++c)
#pragma unroll
            for (int j = 0; j < 8; ++j)
                zv[tl][c * 8 + j] = zbase[(size_t)(c * 32 + g * 8 + j) * 4096 + row];
    }

    frag[t] = c0a; frag[256 + t] = c0b; frag[512 + t] = c0c; frag[768 + t] = c0d;
    en_l[t] = ena; en_l[t + 256] = enb;

    // split-bf16 A-fragments + zn (partial + 4-lane tree; k3/k4 use the SAME value)
    bf16x8 zh[2][2], zl[2][2];
#pragma unroll
    for (int tl = 0; tl < 2; ++tl) {
        float pz = 0.f;
#pragma unroll
        for (int c = 0; c < 2; ++c) {
            unsigned hh[8], hl[8];
#pragma unroll
            for (int j = 0; j < 8; ++j) {
                float x = zv[tl][c * 8 + j];
                pz = fmaf(x, x, pz);
                unsigned h = f32_to_bf16_rne(x);
                float hf = __uint_as_float(h << 16);
                hh[j] = h;
                hl[j] = f32_to_bf16_rne(x - hf);
            }
            frag_cast uh, ul;
#pragma unroll
            for (int i = 0; i < 4; ++i) {
                uh.i[i] = (int)(hh[2 * i] | (hh[2 * i + 1] << 16));
                ul.i[i] = (int)(hl[2 * i] | (hl[2 * i + 1] << 16));
            }
            zh[tl][c] = uh.h;
            zl[tl][c] = ul.h;
        }
        pz += __shfl_xor(pz, 16);
        pz += __shfl_xor(pz, 32);
        if (g == 0) {
            zn_l[w * 32 + tl * 16 + klane] = pz;
            zn_g[n0 + w * 32 + tl * 16 + klane] = pz;
        }
    }
    __syncthreads();   // frag buf0 + en_l + zn_l visible

    f32x4 zn4[2];
    zn4[0] = *(const f32x4*)&zn_l[w * 32 + g * 4];
    zn4[1] = *(const f32x4*)&zn_l[w * 32 + 16 + g * 4];
    const float emax = emaxp[0];

    float m1[2][4], m2[2][4];
    int i1[2][4];
#pragma unroll
    for (int tl = 0; tl < 2; ++tl)
#pragma unroll
        for (int r = 0; r < 4; ++r) { m1[tl][r] = 3.4e38f; m2[tl][r] = 3.4e38f; i1[tl][r] = 0; }

    f32x4 zero = {0.f, 0.f, 0.f, 0.f};
    i32x4 lA0, lA1, lB0, lB1;

    // ---- main: 8 chunks x 4 kt; dbuf, 1 barrier/chunk (readers of buf^1 are barrier-separated)
    for (int c0 = 0; c0 < 8; ++c0) {
        const int buf = c0 & 1;
        if (c0 < 7) {   // issue next chunk's global loads (hide under this chunk's MFMA)
            int base = (c0 + 1) * 512;
            lA0 = efA_[base + t];       lA1 = efA_[base + 256 + t];
            lB0 = efB_[base + t];       lB1 = efB_[base + 256 + t];
        }
        if (c0 > 0) __syncthreads();   // chunk c0 writes visible; c0=0 synced by prologue

        const bf16x8* fh = (const bf16x8*)&frag[buf * 1024];
        const bf16x8* fl = (const bf16x8*)&frag[buf * 1024 + 512];
#pragma unroll
        for (int ktl = 0; ktl < 4; ++ktl) {
            bf16x8 e0h = fh[(ktl * 2 + 0) * 64 + lane];
            bf16x8 e1h = fh[(ktl * 2 + 1) * 64 + lane];
            bf16x8 e0l = fl[(ktl * 2 + 0) * 64 + lane];
            bf16x8 e1l = fl[(ktl * 2 + 1) * 64 + lane];
            int k = (c0 * 4 + ktl) * 16 + klane;
            float enk = en_l[k];
#pragma unroll
            for (int tl = 0; tl < 2; ++tl) {
                f32x4 acc = __builtin_amdgcn_mfma_f32_16x16x32_bf16(zh[tl][0], e0h, zero, 0, 0, 0);
                acc = __builtin_amdgcn_mfma_f32_16x16x32_bf16(zh[tl][1], e1h, acc, 0, 0, 0);
                acc = __builtin_amdgcn_mfma_f32_16x16x32_bf16(zh[tl][0], e0l, acc, 0, 0, 0);
                acc = __builtin_amdgcn_mfma_f32_16x16x32_bf16(zh[tl][1], e1l, acc, 0, 0, 0);
                acc = __builtin_amdgcn_mfma_f32_16x16x32_bf16(zl[tl][0], e0h, acc, 0, 0, 0);
                acc = __builtin_amdgcn_mfma_f32_16x16x32_bf16(zl[tl][1], e1h, acc, 0, 0, 0);
#pragma unroll
                for (int r = 0; r < 4; ++r) {
                    float d = fmaf(-2.f, acc[r], zn4[tl][r] + enk);  // refine-path rounding
                    float o1 = m1[tl][r];
                    i1[tl][r] = (d < o1) ? k : i1[tl][r];
                    m2[tl][r] = fminf(m2[tl][r], fmaxf(o1, d));
                    m1[tl][r] = fminf(o1, d);
                }
            }
        }
        if (c0 < 7) {   // write next chunk into other buffer (its readers were pre-barrier)
            int base2 = ((c0 + 1) & 1) * 1024;
            frag[base2 + t]             = lA0;
            frag[base2 + 256 + t]       = lA1;
            frag[base2 + 512 + t]       = lB0;
            frag[base2 + 512 + 256 + t] = lB1;
        }
    }

    // reduce across the 16 code-lanes: xor 1,2,4,8
#pragma unroll
    for (int sh = 1; sh <= 8; sh <<= 1) {
#pragma unroll
        for (int tl = 0; tl < 2; ++tl)
#pragma unroll
            for (int r = 0; r < 4; ++r) {
                float om1 = __shfl_xor(m1[tl][r], sh);
                int oi1 = __shfl_xor(i1[tl][r], sh);
                float om2 = __shfl_xor(m2[tl][r], sh);
                float hi = fmaxf(m1[tl][r], om1);
                m2[tl][r] = fminf(fminf(m2[tl][r], om2), hi);
                i1[tl][r] = (om1 < m1[tl][r]) ? oi1 : i1[tl][r];
                m1[tl][r] = fminf(m1[tl][r], om1);
            }
    }

    if (klane == 0) {
#pragma unroll
        for (int tl = 0; tl < 2; ++tl) {
            int rowbase = n0 + w * 32 + tl * 16 + g * 4;
            i32x4 idx4;
#pragma unroll
            for (int r = 0; r < 4; ++r) idx4[r] = i1[tl][r];
            *(i32x4*)(out + rowbase) = idx4;
#pragma unroll
            for (int r = 0; r < 4; ++r) {
                float zz = zn4[tl][r];
                // |split-mfma dist - fp32 dist| bound (~3x margin), validated r5-r7
                float W = fmaf(sqrtf(zz) * emax, 1.0e-4f, zz * 1.0e-6f);
                if (m2[tl][r] - m1[tl][r] <= W) {
                    int pos = atomicAdd(cnt, 1);
                    list[pos] = rowbase + r;
                }
            }
        }
    }
}

// ---------------- K4: exact fp32 refine, one wave per listed row ----------------
__global__ __launch_bounds__(256) void k4_refine(
    const float* __restrict__ z, const float* __restrict__ emb,
    const float* __restrict__ en, const float* __restrict__ zn_g,
    const int* __restrict__ list, const int* __restrict__ cnt,
    int* __restrict__ out) {
    __shared__ float zrow[4][64];
    int t = threadIdx.x;
    int w = t >> 6, lane = t & 63;
    int nlist = cnt[0];
    for (int li = blockIdx.x * 4 + w; li < nlist; li += gridDim.x * 4) {
        int row = list[li];
        int b = row >> 12, hw = row & 4095;
        const float* zp = z + (size_t)b * (DDIM * 4096) + hw;
        zrow[w][lane] = zp[(size_t)lane * 4096];
        float zn = zn_g[row];
        float best = 3.4e38f;
        int bi = 0;
#pragma unroll 1
        for (int kk = 0; kk < 8; ++kk) {
            int k = lane * 8 + kk;
            const float* e0 = emb + k * DDIM;
            float acc = 0.f;
#pragma unroll
            for (int d = 0; d < DDIM; ++d) acc = fmaf(e0[d], zrow[w][d], acc);
            float dist = fmaf(-2.f, acc, zn + en[k]);
            if (dist < best) { best = dist; bi = k; }   // ascending k: first-occurrence
        }
        unsigned long long key =
            ((unsigned long long)__float_as_uint(best) << 32) | (unsigned)bi;
#pragma unroll
        for (int sh = 32; sh; sh >>= 1) {
            unsigned long long o = __shfl_xor(key, sh);
            key = (o < key) ? o : key;
        }
        if (lane == 0) out[row] = (int)(key & 0xFFFFFFFFull);
    }
}

// ---------------- fallback (round-1, known-good) ----------------
__global__ void fb_enorm(const float* __restrict__ emb, float* __restrict__ en) {
    int k = blockIdx.x * blockDim.x + threadIdx.x;
    if (k < KCODES) {
        float s = 0.f;
#pragma unroll
        for (int d = 0; d < DDIM; ++d) { float e = emb[k * DDIM + d]; s = fmaf(e, e, s); }
        en[k] = s;
    }
}
__global__ __launch_bounds__(256) void fb_argmin(const float* __restrict__ z,
                                                 const float* __restrict__ emb,
                                                 const float* __restrict__ en,
                                                 int* __restrict__ out, int nrows) {
    int n = blockIdx.x * blockDim.x + threadIdx.x;
    if (n >= nrows) return;
    int b = n >> 12, hw = n & 4095;
    const float* zp = z + (size_t)b * (DDIM * 4096) + hw;
    float zr[DDIM];
#pragma unroll
    for (int d = 0; d < DDIM; ++d) zr[d] = zp[(size_t)d * 4096];
    float zn = 0.f;
#pragma unroll
    for (int d = 0; d < DDIM; ++d) zn = fmaf(zr[d], zr[d], zn);
    float best = 3.4e38f; int bi = 0;
    for (int k0 = 0; k0 < KCODES; k0 += 8) {
        float acc[8];
#pragma unroll
        for (int kk = 0; kk < 8; ++kk) acc[kk] = 0.f;
        const float* e0 = emb + k0 * DDIM;
#pragma unroll
        for (int d = 0; d < DDIM; ++d) {
            float zd = zr[d];
#pragma unroll
            for (int kk = 0; kk < 8; ++kk) acc[kk] = fmaf(e0[kk * DDIM + d], zd, acc[kk]);
        }
#pragma unroll
        for (int kk = 0; kk < 8; ++kk) {
            float dist = fmaf(-2.f, acc[kk], zn + en[k0 + kk]);
            if (dist < best) { best = dist; bi = k0 + kk; }
        }
    }
    out[n] = bi;
}

extern "C" void kernel_launch(void* const* d_in, const int* in_sizes, int n_in,
                              void* d_out, int out_size, void* d_ws, size_t ws_size,
                              hipStream_t stream) {
    const float* z   = (const float*)d_in[0];   // [32,64,64,64] fp32
    const float* emb = (const float*)d_in[1];   // [512,64] fp32
    int* out = (int*)d_out;                     // 131072 int32

    const size_t SZ_EF   = 32 * 2 * 64 * 16;    // 64 KB each
    const size_t SZ_EN   = KCODES * 4;
    const size_t SZ_ZN   = (size_t)NROWS * 4;
    const size_t SZ_EMAX = 64;
    const size_t SZ_LIST = (size_t)NROWS * 4;
    const size_t SZ_CNT  = 64;
    const size_t NEED = 2 * SZ_EF + SZ_EN + SZ_ZN + SZ_EMAX + SZ_LIST + SZ_CNT;  // ~1.2 MB

    if (ws_size < NEED) {   // safety net: round-1 path
        float* en = (float*)d_ws;
        fb_enorm<<<2, 256, 0, stream>>>(emb, en);
        fb_argmin<<<NROWS / 256, 256, 0, stream>>>(z, emb, en, out, NROWS);
        return;
    }

    char* p = (char*)d_ws;
    i32x4* efA = (i32x4*)p;   p += SZ_EF;
    i32x4* efB = (i32x4*)p;   p += SZ_EF;
    float* en  = (float*)p;   p += SZ_EN;
    float* zn  = (float*)p;   p += SZ_ZN;
    float* emaxp = (float*)p; p += SZ_EMAX;
    int* list = (int*)p;      p += SZ_LIST;
    int* cnt  = (int*)p;

    k1_enorm<<<1, 512, 0, stream>>>(emb, en, emaxp);
    k1_efrag<<<32, 128, 0, stream>>>(emb, efA, efB);
    hipMemsetAsync(cnt, 0, 4, stream);

    k3_fused<<<NROWS / 128, 256, 0, stream>>>(z, efA, efB, en, zn, emaxp, out, list, cnt);
    k4_refine<<<512, 256, 0, stream>>>(z, emb, en, zn, list, cnt, out);
}